// Round 11
// baseline (257.992 us; speedup 1.0000x reference)
//
#include <hip/hip_runtime.h>
#include <hip/hip_bf16.h>
#include <math.h>

// Problem constants
#define B_    256
#define L_    200
#define H_    256
#define MAXT  256
#define SIXH  1536
#define FOURH 1024
#define NPOS  (B_ * L_)   // 51200

typedef __attribute__((ext_vector_type(8))) short short8;
typedef __attribute__((ext_vector_type(4))) float f32x4;

typedef __attribute__((address_space(3))) void lds_void;
typedef const __attribute__((address_space(1))) void gbl_void;

#define ASM_BAR() asm volatile("s_barrier" ::: "memory")
#define VMCNT3()  asm volatile("s_waitcnt vmcnt(3)" ::: "memory")
#define VMCNT0()  asm volatile("s_waitcnt vmcnt(0)" ::: "memory")

// ---------------------------------------------------------------------------
// Parallel exclusive prefix-sum of lengths.
// ---------------------------------------------------------------------------
__global__ void scan_offsets(const int* __restrict__ lengths,
                             int* __restrict__ offsets) {
  int t = threadIdx.x;           // 0..255
  int lane = t & 63, wv = t >> 6;
  int len = lengths[t];
  int s = len;
#pragma unroll
  for (int o = 1; o < 64; o <<= 1) {
    int v = __shfl_up(s, o);
    if (lane >= o) s += v;
  }
  __shared__ int wsum[4];
  if (lane == 63) wsum[wv] = s;
  __syncthreads();
  int pre = 0;
#pragma unroll
  for (int k = 0; k < 4; k++)
    if (k < wv) pre += wsum[k];
  s += pre;
  offsets[t] = s - len;  // exclusive
  if (t == 255) offsets[B_] = s;
}

// ---------------------------------------------------------------------------
// Zero the pad rows of x: rows [total, roundup256(total))
// ---------------------------------------------------------------------------
__global__ void zero_pad_x(__hip_bfloat16* __restrict__ x,
                           const int* __restrict__ offsets) {
  int total = offsets[B_];
  int padded = (total + 255) & ~255;
  int row = total + blockIdx.x;
  if (row >= padded) return;
  int t = threadIdx.x;
#pragma unroll
  for (int j = 0; j < 6; j++)
    x[(size_t)row * SIXH + j * 256 + t] = __float2bfloat16(0.0f);
}

// ---------------------------------------------------------------------------
// Per compacted row: absolute output slot b*MAXT+p (or -1).
// ---------------------------------------------------------------------------
__global__ void tpos_kernel(const int* __restrict__ gids,
                            const int* __restrict__ lengths,
                            const int* __restrict__ offsets,
                            int* __restrict__ tpos) {
  int b = blockIdx.x, t = threadIdx.x;
  __shared__ int g[L_];
  int len = lengths[b];
  for (int l = t; l < len; l += 64) g[l] = gids[b * L_ + l];
  __syncthreads();
  if (t != 0) return;
  int base = offsets[b];
  int nsep = 0;
  for (int l = 0; l + 1 < len; l++)
    if (g[l] != g[l + 1]) nsep++;
  int total = len + nsep;
  int off = MAXT - total;
  int sb = 0;
  for (int l = 0; l < len; l++) {
    int ti = off + l + sb;
    tpos[base + l] = (ti >= 0) ? (b * MAXT + ti) : -1;
    if (l + 1 < len && g[l] != g[l + 1]) sb++;
  }
}

// ---------------------------------------------------------------------------
// Fused transpose+bf16 of BOTH weights in one launch.
// ---------------------------------------------------------------------------
__global__ void transpose_both(const float* __restrict__ w1,
                               __hip_bfloat16* __restrict__ w1t,
                               const float* __restrict__ w2,
                               __hip_bfloat16* __restrict__ w2t) {
  __shared__ float tile[32][33];
  int id = blockIdx.x;
  const float* in; __hip_bfloat16* out; int R, C, tc, tr;
  if (id < 1536) {
    in = w1; out = w1t; R = 1536; C = 1024; tc = id & 31; tr = id >> 5;
  } else {
    int j = id - 1536;
    in = w2; out = w2t; R = 1024; C = 256; tc = j & 7; tr = j >> 3;
  }
  int tx = threadIdx.x & 31, ty = threadIdx.x >> 5;
#pragma unroll
  for (int i = 0; i < 4; i++)
    tile[ty + i * 8][tx] = in[(size_t)(tr * 32 + ty + i * 8) * C + tc * 32 + tx];
  __syncthreads();
#pragma unroll
  for (int i = 0; i < 4; i++)
    out[(size_t)(tc * 32 + ty + i * 8) * R + tr * 32 + tx] =
        __float2bfloat16(tile[tx][ty + i * 8]);
}

// ---------------------------------------------------------------------------
// Fused embedding gather + concat + LayerNorm -> x bf16 [row][1536]
// ---------------------------------------------------------------------------
__global__ void embed_ln_kernel(const int* __restrict__ tok0,
                                const int* __restrict__ tok1,
                                const int* __restrict__ tok2,
                                const int* __restrict__ tok3,
                                const int* __restrict__ tgap,
                                const int* __restrict__ gid,
                                const int* __restrict__ lengths,
                                const int* __restrict__ offsets,
                                const float* __restrict__ token_emb,
                                const float* __restrict__ tg_emb,
                                const float* __restrict__ g_emb,
                                const float* __restrict__ gamma,
                                const float* __restrict__ beta,
                                __hip_bfloat16* __restrict__ xout) {
  int l = blockIdx.x, b = blockIdx.y;
  if (l >= lengths[b]) return;
  int pos = b * L_ + l;
  int row = offsets[b] + l;
  int t = threadIdx.x;
  int wv = t >> 6;
  int ln = t & 63;
  int c4 = ln * 4;

  const float* tab;
  int idx;
  if (wv == 0)      { tab = token_emb; idx = tok0[pos]; }
  else if (wv == 1) { tab = token_emb; idx = tok1[pos]; }
  else if (wv == 2) { tab = token_emb; idx = tok2[pos]; }
  else if (wv == 3) { tab = token_emb; idx = tok3[pos]; }
  else if (wv == 4) { tab = tg_emb;    idx = min(max(tgap[pos], 0), 64); }
  else              { tab = g_emb;     idx = gid[pos]; }

  float4 v = *(const float4*)&tab[(size_t)idx * H_ + c4];

  float s = v.x + v.y + v.z + v.w;
  float q = v.x * v.x + v.y * v.y + v.z * v.z + v.w * v.w;
#pragma unroll
  for (int o = 32; o; o >>= 1) { s += __shfl_down(s, o); q += __shfl_down(q, o); }
  __shared__ float ps[6], pq[6];
  if (ln == 0) { ps[wv] = s; pq[wv] = q; }
  __syncthreads();
  float ts = 0.f, tq = 0.f;
#pragma unroll
  for (int k = 0; k < 6; k++) { ts += ps[k]; tq += pq[k]; }
  float mu = ts * (1.0f / 1536.0f);
  float var = tq * (1.0f / 1536.0f) - mu * mu;
  float rstd = rsqrtf(var + 1e-5f);

  int cbase = wv * 256 + c4;
  float4 gm = *(const float4*)&gamma[cbase];
  float4 bt = *(const float4*)&beta[cbase];
  float y0 = (v.x - mu) * rstd * gm.x + bt.x;
  float y1 = (v.y - mu) * rstd * gm.y + bt.y;
  float y2 = (v.z - mu) * rstd * gm.z + bt.z;
  float y3 = (v.w - mu) * rstd * gm.w + bt.w;
  __hip_bfloat16 h0 = __float2bfloat16(y0), h1 = __float2bfloat16(y1);
  __hip_bfloat16 h2 = __float2bfloat16(y2), h3 = __float2bfloat16(y3);
  ushort4 pk;
  pk.x = *(unsigned short*)&h0; pk.y = *(unsigned short*)&h1;
  pk.z = *(unsigned short*)&h2; pk.w = *(unsigned short*)&h3;
  *(ushort4*)&xout[(size_t)row * SIXH + cbase] = pk;
}

// ---------------------------------------------------------------------------
// GEMM1 (R11: deep-pipelined ring). Geometry identical to R10 (256x128 tile,
// 8 waves of 64x64, 2 blocks/CU, XCD-grouped grid, verified swizzle+stage
// mapping). R10 post-mortem: no pipe >45% busy -> sync/latency-bound (2 bars
// + 1-iter vmcnt distance per BK=32). R11:
//   * 3-slot LDS ring (A 3x16KB, B 3x8KB = 72KB <= 80KB, keeps 2 blocks/CU)
//   * stage issued 2 iters ahead of use (issue-to-use ~2 iters)
//   * ONE barrier per iter (restage target last read before PREVIOUS iter's
//     barrier -> safe); barrier count halved
//   * no clamp in main loop (last 2 iters peeled); stage addr = ptr += 64B
// vmcnt(3) per iter retires iter-(i-1)'s 3 stages, keeps iter-i's in flight;
// every wave waits before the barrier -> cross-wave visibility (R4 pattern).
// ---------------------------------------------------------------------------
__global__ __launch_bounds__(512, 4)
void gemm1_ring(const __hip_bfloat16* __restrict__ A,
                const __hip_bfloat16* __restrict__ Bt,
                const float* __restrict__ bias,
                __hip_bfloat16* __restrict__ out,
                const int* __restrict__ total_ptr) {
  constexpr int K = SIXH;      // 1536
  constexpr int NS = K / 32;   // 48 K-steps
  constexpr int N = FOURH;     // 1024

  __shared__ __align__(16) char lds[73728];  // A: 3x16KB @0; B: 3x8KB @49152

  int total = total_ptr[0];
  int padded = (total + 255) & ~255;
  int num_mt = padded >> 8;

  int flat = blockIdx.y * 8 + blockIdx.x;  // 0..1599
  int xcd = flat & 7;
  int j = flat >> 3;                       // 0..199
  int nt = j & 7;                          // 0..7 (128-col tiles)
  int mt = (j >> 3) * 8 + xcd;             // same-mt siblings share XCD
  if (mt >= num_mt) return;
  int m0 = mt * 256;
  int n0 = nt * 128;

  int tid = threadIdx.x;
  int lane = tid & 63;
  int w = tid >> 6;
  int wave_m = w >> 1;     // 0..3 (64-row slabs)
  int wave_n = w & 1;      // 0..1 (64-col slabs)

  int r15 = lane & 15, g = lane >> 4;
  int slot_r = (((r15 & 1) << 2) | g) ^ (r15 >> 1);
  int lane_off = (r15 >> 1) * 128 + slot_r * 16;

  int s0 = (tid & 7) ^ ((tid >> 3) & 7);
  int scol = (s0 & 3) * 8;
  int row0 = ((tid >> 3) << 1) + (s0 >> 2);  // 0..127

  float bv4[4];
#pragma unroll
  for (int ni = 0; ni < 4; ni++)
    bv4[ni] = bias[n0 + wave_n * 64 + ni * 16 + r15];

  // per-wave global stage pointers; advance 64 B (=32 cols bf16) per K-step
  const char* gA0 = (const char*)(A + (size_t)(m0 + row0) * K + scol);
  const char* gA1 = (const char*)(A + (size_t)(m0 + row0 + 128) * K + scol);
  const char* gB  = (const char*)(Bt + (size_t)(n0 + row0) * K + scol);

#define STAGE_AT(kb, aoff, boff)                                               \
  do {                                                                         \
    __builtin_amdgcn_global_load_lds((gbl_void*)(gA0 + (kb)),                  \
                                     (lds_void*)(lds + (aoff) + w * 1024),     \
                                     16, 0, 0);                                \
    __builtin_amdgcn_global_load_lds(                                          \
        (gbl_void*)(gA1 + (kb)), (lds_void*)(lds + (aoff) + 8192 + w * 1024),  \
        16, 0, 0);                                                             \
    __builtin_amdgcn_global_load_lds(                                          \
        (gbl_void*)(gB + (kb)), (lds_void*)(lds + 49152 + (boff) + w * 1024),  \
        16, 0, 0);                                                             \
  } while (0)

  f32x4 acc[4][4] = {};

  // prologue: ks0 -> slot0, ks1 -> slot1
  STAGE_AT(0, 0, 0);
  STAGE_AT(64, 16384, 8192);
  VMCNT3();   // ks0's 3 retired (own wave); cross-wave via barrier
  ASM_BAR();

  int rdA = 0, rdB = 0;          // read-slot byte offsets (cycle 0,16K,32K / 0,8K,16K)
  int stA = 32768, stB = 16384;  // stage-slot offsets (= read + 2 slots)
  int kb = 128;                  // stage byte offset = (ks+2)*64

  for (int ks = 0; ks < NS - 2; ++ks) {
    char* Ad = lds + rdA;
    char* Bd = lds + 49152 + rdB;

    short8 a[4], b[4];
#pragma unroll
    for (int ni = 0; ni < 4; ni++)
      b[ni] = *(const short8*)(Bd + (wave_n * 64 + ni * 16) * 64 + lane_off);
#pragma unroll
    for (int mi = 0; mi < 4; mi++)
      a[mi] = *(const short8*)(Ad + (wave_m * 64 + mi * 16) * 64 + lane_off);

    STAGE_AT(kb, stA, stB);   // slot last read at iter ks-1 (pre-barrier) -> safe

    __builtin_amdgcn_s_setprio(1);
#pragma unroll
    for (int mi = 0; mi < 4; mi++)
#pragma unroll
      for (int ni = 0; ni < 4; ni++)
        acc[mi][ni] = __builtin_amdgcn_mfma_f32_16x16x32_bf16(a[mi], b[ni],
                                                              acc[mi][ni], 0, 0, 0);
    __builtin_amdgcn_s_setprio(0);

    VMCNT3();   // retire iter ks-1's stages (needed at iter ks+1); keep ks's
    ASM_BAR();  // single barrier per iter

    kb += 64;
    rdA = (rdA == 32768) ? 0 : rdA + 16384;
    rdB = (rdB == 16384) ? 0 : rdB + 8192;
    stA = (stA == 32768) ? 0 : stA + 16384;
    stB = (stB == 16384) ? 0 : stB + 8192;
  }

  // peeled iter NS-2: slot staged at NS-4, retired+bar'd at end of NS-3
  {
    char* Ad = lds + rdA;
    char* Bd = lds + 49152 + rdB;
    short8 a[4], b[4];
#pragma unroll
    for (int ni = 0; ni < 4; ni++)
      b[ni] = *(const short8*)(Bd + (wave_n * 64 + ni * 16) * 64 + lane_off);
#pragma unroll
    for (int mi = 0; mi < 4; mi++)
      a[mi] = *(const short8*)(Ad + (wave_m * 64 + mi * 16) * 64 + lane_off);
#pragma unroll
    for (int mi = 0; mi < 4; mi++)
#pragma unroll
      for (int ni = 0; ni < 4; ni++)
        acc[mi][ni] = __builtin_amdgcn_mfma_f32_16x16x32_bf16(a[mi], b[ni],
                                                              acc[mi][ni], 0, 0, 0);
    VMCNT0();   // retire NS-3's stages (slot for final iter)
    ASM_BAR();
    rdA = (rdA == 32768) ? 0 : rdA + 16384;
    rdB = (rdB == 16384) ? 0 : rdB + 8192;
  }
  // peeled iter NS-1
  {
    char* Ad = lds + rdA;
    char* Bd = lds + 49152 + rdB;
    short8 a[4], b[4];
#pragma unroll
    for (int ni = 0; ni < 4; ni++)
      b[ni] = *(const short8*)(Bd + (wave_n * 64 + ni * 16) * 64 + lane_off);
#pragma unroll
    for (int mi = 0; mi < 4; mi++)
      a[mi] = *(const short8*)(Ad + (wave_m * 64 + mi * 16) * 64 + lane_off);
#pragma unroll
    for (int mi = 0; mi < 4; mi++)
#pragma unroll
      for (int ni = 0; ni < 4; ni++)
        acc[mi][ni] = __builtin_amdgcn_mfma_f32_16x16x32_bf16(a[mi], b[ni],
                                                              acc[mi][ni], 0, 0, 0);
  }

  // epilogue: D mapping col = lane&15, row = 4*(lane>>4)+reg
  int r0 = g * 4;
#pragma unroll
  for (int mi = 0; mi < 4; mi++)
#pragma unroll
    for (int ni = 0; ni < 4; ni++) {
      int col = n0 + wave_n * 64 + ni * 16 + r15;
      float bv = bv4[ni];
#pragma unroll
      for (int r = 0; r < 4; r++) {
        int row = m0 + wave_m * 64 + mi * 16 + r0 + r;
        float v = acc[mi][ni][r] + bv;
        v = v / (1.0f + __expf(-v));  // silu
        out[(size_t)row * N + col] = __float2bfloat16(v);
      }
    }
#undef STAGE_AT
}

// ---------------------------------------------------------------------------
// GEMM2 with fused scatter epilogue (proven 128x128 form).
// ---------------------------------------------------------------------------
__global__ void gemm2_scatter(const __hip_bfloat16* __restrict__ A,
                              const __hip_bfloat16* __restrict__ Bt,
                              const float* __restrict__ bias,
                              const int* __restrict__ tpos,
                              const float* __restrict__ pos_emb,
                              float* __restrict__ out,
                              const int* __restrict__ total_ptr,
                              int N, int K) {
  int m0 = blockIdx.y * 128;
  int total = total_ptr[0];
  int padded = (total + 127) & ~127;
  if (m0 >= padded) return;

  __shared__ __hip_bfloat16 As[128 * 64];
  __shared__ __hip_bfloat16 Bs[128 * 64];
  int n0 = blockIdx.x * 128;
  int tid = threadIdx.x;
  int lane = tid & 63, wid = tid >> 6;
  int wm = (wid >> 1) * 64, wn = (wid & 1) * 64;

  int srow = (lane >> 3);
  int scol = (lane & 7) * 8;

  f32x4 acc[4][4] = {};

  for (int k0 = 0; k0 < K; k0 += 64) {
#pragma unroll
    for (int i = 0; i < 4; i++) {
      int c = wid * 4 + i;
      int row = c * 8 + srow;
      __builtin_amdgcn_global_load_lds(
          (gbl_void*)&A[(size_t)(m0 + row) * K + k0 + scol],
          (lds_void*)(As + c * 512), 16, 0, 0);
      __builtin_amdgcn_global_load_lds(
          (gbl_void*)&Bt[(size_t)(n0 + row) * K + k0 + scol],
          (lds_void*)(Bs + c * 512), 16, 0, 0);
    }
    __syncthreads();
#pragma unroll
    for (int kk = 0; kk < 64; kk += 32) {
      short8 a[4], bb[4];
#pragma unroll
      for (int m = 0; m < 4; m++)
        a[m] = *(const short8*)&As[(wm + m * 16 + (lane & 15)) * 64 + kk +
                                   8 * (lane >> 4)];
#pragma unroll
      for (int n = 0; n < 4; n++)
        bb[n] = *(const short8*)&Bs[(wn + n * 16 + (lane & 15)) * 64 + kk +
                                    8 * (lane >> 4)];
#pragma unroll
      for (int m = 0; m < 4; m++)
#pragma unroll
        for (int n = 0; n < 4; n++)
          acc[m][n] = __builtin_amdgcn_mfma_f32_16x16x32_bf16(a[m], bb[n],
                                                              acc[m][n], 0, 0, 0);
    }
    __syncthreads();
  }

  int r0 = (lane >> 4) * 4;
  int cc = lane & 15;
#pragma unroll
  for (int m = 0; m < 4; m++) {
#pragma unroll
    for (int r = 0; r < 4; r++) {
      int row = m0 + wm + m * 16 + r0 + r;
      if (row >= total) continue;
      int pa = tpos[row];
      if (pa < 0) continue;
      int p = pa & (MAXT - 1);
#pragma unroll
      for (int n = 0; n < 4; n++) {
        int col = n0 + wn + n * 16 + cc;
        float v = acc[m][n][r] + bias[col] + pos_emb[p * H_ + col];
        out[(size_t)pa * H_ + col] = v;
      }
    }
  }
}

// ---------------------------------------------------------------------------
// merge2: sep rows (sep_token + pos_emb), zero-fill empty positions, mm.
// ---------------------------------------------------------------------------
__global__ void merge2_kernel(const int* __restrict__ gids,
                              const int* __restrict__ lengths,
                              const float* __restrict__ sep_token,
                              const float* __restrict__ pos_emb,
                              float* __restrict__ out) {
  int b = blockIdx.x, t = threadIdx.x;
  __shared__ signed char src[MAXT];
  __shared__ int g[L_];
  __shared__ int sh_total;
  int len = lengths[b];
  src[t] = 0;
  for (int l = t; l < len; l += 256) g[l] = gids[b * L_ + l];
  __syncthreads();
  if (t == 0) {
    int nsep = 0;
    for (int l = 0; l + 1 < len; l++)
      if (g[l] != g[l + 1]) nsep++;
    int total = len + nsep;
    sh_total = total;
    int off = MAXT - total;
    int sb = 0;
    for (int l = 0; l < len; l++) {
      int ti = off + l + sb;
      if (ti >= 0) src[ti] = 2;
      if (l + 1 < len && g[l] != g[l + 1]) {
        if (ti + 1 >= 0) src[ti + 1] = 1;
        sb++;
      }
    }
  }
  __syncthreads();
  int total = sh_total;
  int mlen = min(total, MAXT);

  int q = t >> 6, lane = t & 63, c4 = lane * 4;
  float4 sep4 = *(const float4*)&sep_token[c4];
  float* orow = out + (size_t)b * MAXT * H_;
  for (int p0 = 0; p0 < MAXT; p0 += 4) {
    int p = p0 + q;
    int s = src[p];
    if (s == 2) continue;
    float4 v;
    if (s == 1) {
      float4 pe = *(const float4*)&pos_emb[p * H_ + c4];
      v.x = sep4.x + pe.x; v.y = sep4.y + pe.y;
      v.z = sep4.z + pe.z; v.w = sep4.w + pe.w;
    } else {
      v.x = 0.f; v.y = 0.f; v.z = 0.f; v.w = 0.f;
    }
    *(float4*)&orow[(size_t)p * H_ + c4] = v;
  }
  float* mm = out + (size_t)B_ * MAXT * H_;
  mm[b * MAXT + t] = (t >= MAXT - mlen) ? 1.0f : 0.0f;
}

// ---------------------------------------------------------------------------
// launch
// ---------------------------------------------------------------------------
extern "C" void kernel_launch(void* const* d_in, const int* in_sizes, int n_in,
                              void* d_out, int out_size, void* d_ws,
                              size_t ws_size, hipStream_t stream) {
  const int* tok0 = (const int*)d_in[0];
  const int* tok1 = (const int*)d_in[1];
  const int* tok2 = (const int*)d_in[2];
  const int* tok3 = (const int*)d_in[3];
  const int* tgap = (const int*)d_in[4];
  const int* gid  = (const int*)d_in[5];
  const int* lengths = (const int*)d_in[6];
  const float* token_emb = (const float*)d_in[7];
  const float* gamma = (const float*)d_in[8];
  const float* beta  = (const float*)d_in[9];
  const float* w1 = (const float*)d_in[10];
  const float* b1 = (const float*)d_in[11];
  const float* w2 = (const float*)d_in[12];
  const float* b2 = (const float*)d_in[13];
  const float* tg_emb = (const float*)d_in[14];
  const float* g_emb  = (const float*)d_in[15];
  const float* pos_emb = (const float*)d_in[16];
  const float* sep_tok = (const float*)d_in[17];

  // workspace layout (bytes):
  //   x     bf16 [<=51200][1536] @ 0          (157,286,400)
  //   tpos  int  [<=51200]       @ 0          (aliases x; written after GEMM1)
  //   h     bf16 [<=51200][1024] @ 157286400  (104,857,600)
  //   w1t   bf16 [1024][1536]    @ 262144000  (  3,145,728)
  //   w2t   bf16 [256][1024]     @ 265289728  (    524,288)
  //   offsets int[257]           @ 265814016  (      1,028)
  const size_t NEEDED = 265815044;
  if (ws_size < NEEDED) return;

  char* ws = (char*)d_ws;
  __hip_bfloat16* x = (__hip_bfloat16*)ws;
  int* tpos = (int*)ws;  // aliases x (x dead after GEMM1)
  __hip_bfloat16* h = (__hip_bfloat16*)(ws + 157286400);
  __hip_bfloat16* w1t = (__hip_bfloat16*)(ws + 262144000);
  __hip_bfloat16* w2t = (__hip_bfloat16*)(ws + 265289728);
  int* offsets = (int*)(ws + 265814016);

  scan_offsets<<<1, 256, 0, stream>>>(lengths, offsets);
  zero_pad_x<<<256, 256, 0, stream>>>(x, offsets);

  transpose_both<<<1792, 256, 0, stream>>>(w1, w1t, w2, w2t);

  embed_ln_kernel<<<dim3(L_, B_), 384, 0, stream>>>(
      tok0, tok1, tok2, tok3, tgap, gid, lengths, offsets, token_emb, tg_emb,
      g_emb, gamma, beta, x);

  gemm1_ring<<<dim3(8, NPOS / 256), 512, 0, stream>>>(x, w1t, b1, h,
                                                      offsets + B_);

  // x now dead -> tpos may overwrite its region
  tpos_kernel<<<B_, 64, 0, stream>>>(gid, lengths, offsets, tpos);

  gemm2_scatter<<<dim3(H_ / 128, NPOS / 128), 256, 0, stream>>>(
      h, w2t, b2, tpos, pos_emb, (float*)d_out, offsets + B_, H_, FOURH);

  merge2_kernel<<<B_, 256, 0, stream>>>(gid, lengths, sep_tok, pos_emb,
                                        (float*)d_out);
}

// Round 12
// 252.451 us; speedup vs baseline: 1.0219x; 1.0219x over previous
//
#include <hip/hip_runtime.h>
#include <hip/hip_bf16.h>
#include <math.h>

// Problem constants
#define B_    256
#define L_    200
#define H_    256
#define MAXT  256
#define SIXH  1536
#define FOURH 1024
#define NPOS  (B_ * L_)   // 51200

typedef __attribute__((ext_vector_type(8))) short short8;
typedef __attribute__((ext_vector_type(4))) float f32x4;

typedef __attribute__((address_space(3))) void lds_void;
typedef const __attribute__((address_space(1))) void gbl_void;

#define ASM_BAR() asm volatile("s_barrier" ::: "memory")
#define VMCNT4()  asm volatile("s_waitcnt vmcnt(4)" ::: "memory")
#define VMCNT0()  asm volatile("s_waitcnt vmcnt(0)" ::: "memory")

// ---------------------------------------------------------------------------
// fused_pre: one kernel replacing scan_offsets + tpos_kernel + zero_pad_x.
// 256 blocks x 256 threads. Every block redundantly computes the prefix sum
// of all 256 lengths in-block (1KB, L2-hot), then block b:
//   - writes offsets[b] (block 0 also offsets[256])
//   - computes tpos for batch b (thread-0 serial scan, g[] preloaded)
//   - zero-pads x row (total + b) if < roundup256(total)
// ---------------------------------------------------------------------------
__global__ void fused_pre(const int* __restrict__ lengths,
                          const int* __restrict__ gids,
                          int* __restrict__ offsets,
                          int* __restrict__ tpos,
                          __hip_bfloat16* __restrict__ x) {
  int b = blockIdx.x, t = threadIdx.x;
  int lane = t & 63, wv = t >> 6;

  // block-local prefix sum over all 256 lengths
  int len_t = lengths[t];
  int s = len_t;
#pragma unroll
  for (int o = 1; o < 64; o <<= 1) {
    int v = __shfl_up(s, o);
    if (lane >= o) s += v;
  }
  __shared__ int wsum[4];
  __shared__ int all_off[257];
  if (lane == 63) wsum[wv] = s;
  __syncthreads();
  int pre = 0;
#pragma unroll
  for (int k = 0; k < 4; k++)
    if (k < wv) pre += wsum[k];
  s += pre;
  all_off[t] = s - len_t;
  if (t == 255) all_off[256] = s;
  __syncthreads();

  int base = all_off[b];
  int total = all_off[256];
  if (t == 0) {
    offsets[b] = base;
    if (b == 0) offsets[B_] = total;
  }

  // tpos for batch b
  __shared__ int g[L_];
  int len = lengths[b];
  for (int l = t; l < len; l += 256) g[l] = gids[b * L_ + l];
  __syncthreads();
  if (t == 0) {
    int nsep = 0;
    for (int l = 0; l + 1 < len; l++)
      if (g[l] != g[l + 1]) nsep++;
    int tot = len + nsep;
    int off = MAXT - tot;
    int sb = 0;
    for (int l = 0; l < len; l++) {
      int ti = off + l + sb;
      tpos[base + l] = (ti >= 0) ? (b * MAXT + ti) : -1;
      if (l + 1 < len && g[l] != g[l + 1]) sb++;
    }
  }

  // zero-pad x row (total + b) if within padded range
  int padded = (total + 255) & ~255;
  int row = total + b;
  if (row < padded) {
#pragma unroll
    for (int j = 0; j < 6; j++)
      x[(size_t)row * SIXH + j * 256 + t] = __float2bfloat16(0.0f);
  }
}

// ---------------------------------------------------------------------------
// Fused transpose+bf16 of BOTH weights in one launch.
// ---------------------------------------------------------------------------
__global__ void transpose_both(const float* __restrict__ w1,
                               __hip_bfloat16* __restrict__ w1t,
                               const float* __restrict__ w2,
                               __hip_bfloat16* __restrict__ w2t) {
  __shared__ float tile[32][33];
  int id = blockIdx.x;
  const float* in; __hip_bfloat16* out; int R, C, tc, tr;
  if (id < 1536) {
    in = w1; out = w1t; R = 1536; C = 1024; tc = id & 31; tr = id >> 5;
  } else {
    int j = id - 1536;
    in = w2; out = w2t; R = 1024; C = 256; tc = j & 7; tr = j >> 3;
  }
  int tx = threadIdx.x & 31, ty = threadIdx.x >> 5;
#pragma unroll
  for (int i = 0; i < 4; i++)
    tile[ty + i * 8][tx] = in[(size_t)(tr * 32 + ty + i * 8) * C + tc * 32 + tx];
  __syncthreads();
#pragma unroll
  for (int i = 0; i < 4; i++)
    out[(size_t)(tc * 32 + ty + i * 8) * R + tr * 32 + tx] =
        __float2bfloat16(tile[tx][ty + i * 8]);
}

// ---------------------------------------------------------------------------
// Fused embedding gather + concat + LayerNorm -> x bf16 [row][1536]
// ---------------------------------------------------------------------------
__global__ void embed_ln_kernel(const int* __restrict__ tok0,
                                const int* __restrict__ tok1,
                                const int* __restrict__ tok2,
                                const int* __restrict__ tok3,
                                const int* __restrict__ tgap,
                                const int* __restrict__ gid,
                                const int* __restrict__ lengths,
                                const int* __restrict__ offsets,
                                const float* __restrict__ token_emb,
                                const float* __restrict__ tg_emb,
                                const float* __restrict__ g_emb,
                                const float* __restrict__ gamma,
                                const float* __restrict__ beta,
                                __hip_bfloat16* __restrict__ xout) {
  int l = blockIdx.x, b = blockIdx.y;
  if (l >= lengths[b]) return;
  int pos = b * L_ + l;
  int row = offsets[b] + l;
  int t = threadIdx.x;
  int wv = t >> 6;
  int ln = t & 63;
  int c4 = ln * 4;

  const float* tab;
  int idx;
  if (wv == 0)      { tab = token_emb; idx = tok0[pos]; }
  else if (wv == 1) { tab = token_emb; idx = tok1[pos]; }
  else if (wv == 2) { tab = token_emb; idx = tok2[pos]; }
  else if (wv == 3) { tab = token_emb; idx = tok3[pos]; }
  else if (wv == 4) { tab = tg_emb;    idx = min(max(tgap[pos], 0), 64); }
  else              { tab = g_emb;     idx = gid[pos]; }

  float4 v = *(const float4*)&tab[(size_t)idx * H_ + c4];

  float s = v.x + v.y + v.z + v.w;
  float q = v.x * v.x + v.y * v.y + v.z * v.z + v.w * v.w;
#pragma unroll
  for (int o = 32; o; o >>= 1) { s += __shfl_down(s, o); q += __shfl_down(q, o); }
  __shared__ float ps[6], pq[6];
  if (ln == 0) { ps[wv] = s; pq[wv] = q; }
  __syncthreads();
  float ts = 0.f, tq = 0.f;
#pragma unroll
  for (int k = 0; k < 6; k++) { ts += ps[k]; tq += pq[k]; }
  float mu = ts * (1.0f / 1536.0f);
  float var = tq * (1.0f / 1536.0f) - mu * mu;
  float rstd = rsqrtf(var + 1e-5f);

  int cbase = wv * 256 + c4;
  float4 gm = *(const float4*)&gamma[cbase];
  float4 bt = *(const float4*)&beta[cbase];
  float y0 = (v.x - mu) * rstd * gm.x + bt.x;
  float y1 = (v.y - mu) * rstd * gm.y + bt.y;
  float y2 = (v.z - mu) * rstd * gm.z + bt.z;
  float y3 = (v.w - mu) * rstd * gm.w + bt.w;
  __hip_bfloat16 h0 = __float2bfloat16(y0), h1 = __float2bfloat16(y1);
  __hip_bfloat16 h2 = __float2bfloat16(y2), h3 = __float2bfloat16(y3);
  ushort4 pk;
  pk.x = *(unsigned short*)&h0; pk.y = *(unsigned short*)&h1;
  pk.z = *(unsigned short*)&h2; pk.w = *(unsigned short*)&h3;
  *(ushort4*)&xout[(size_t)row * SIXH + cbase] = pk;
}

// ---------------------------------------------------------------------------
// GEMM1: R9 version verbatim (best measured: 103.6us, FETCH 64.7MB).
// Persistent, XCD-sibling-grouped, 256x256 tile, BK=64, 8 waves, 2-barrier
// K-loop, counted vmcnt(4), XOR-swizzled LDS (0 conflicts).
// ---------------------------------------------------------------------------
__global__ __launch_bounds__(512, 2)
void gemm1_8ph(const __hip_bfloat16* __restrict__ A,
               const __hip_bfloat16* __restrict__ Bt,
               const float* __restrict__ bias,
               __hip_bfloat16* __restrict__ out,
               const int* __restrict__ total_ptr) {
  constexpr int K = SIXH;     // 1536
  constexpr int NT = K / 64;  // 24 K-tiles
  constexpr int N = FOURH;    // 1024

  extern __shared__ __align__(16) char lds[];

  int total = total_ptr[0];
  int padded = (total + 255) & ~255;
  int num_mt = padded >> 8;

  int bid = blockIdx.x;        // 0..255
  int xcd = bid & 7;
  int slot = bid >> 3;         // 0..31
  int nt = slot & 3;           // 0..3
  int mtb = slot >> 2;         // 0..7
  int n0 = nt * 256;

  int tid = threadIdx.x;
  int lane = tid & 63;
  int w = tid >> 6;
  int wave_m = w >> 2;
  int wave_n = w & 3;

  int r15 = lane & 15, g = lane >> 4;
  int slot_r = (((r15 & 1) << 2) | g) ^ (r15 >> 1);
  int lane_off = (r15 >> 1) * 128 + slot_r * 16;

  int s0 = (tid & 7) ^ ((tid >> 3) & 7);
  int scol = (s0 & 3) * 8;
  int row0 = ((tid >> 3) << 1) + (s0 >> 2);
  int ldst0 = w * 1024;

  float bv4[4];
#pragma unroll
  for (int ni = 0; ni < 4; ni++)
    bv4[ni] = bias[n0 + wave_n * 64 + ni * 16 + r15];

#define REGA(d, h) (lds + (d) * 65536 + (h) * 16384)
#define REGB(d, h) (lds + (d) * 65536 + 32768 + (h) * 16384)

#define STAGE(P, t0, kt, h, rb)                                                \
  do {                                                                         \
    __builtin_amdgcn_global_load_lds(                                          \
        (gbl_void*)((P) + (size_t)((t0) + row0) * K + (kt) * 64 + (h) * 32 +   \
                    scol),                                                     \
        (lds_void*)((rb) + ldst0), 16, 0, 0);                                  \
    __builtin_amdgcn_global_load_lds(                                          \
        (gbl_void*)((P) + (size_t)((t0) + row0 + 128) * K + (kt) * 64 +        \
                    (h) * 32 + scol),                                          \
        (lds_void*)((rb) + 8192 + ldst0), 16, 0, 0);                           \
  } while (0)

  for (int mt = xcd + 8 * mtb; mt < num_mt; mt += 64) {
    int m0 = mt * 256;

    f32x4 acc[8][4] = {};

    STAGE(A, m0, 0, 0, REGA(0, 0));
    STAGE(Bt, n0, 0, 0, REGB(0, 0));
    STAGE(A, m0, 0, 1, REGA(0, 1));
    STAGE(Bt, n0, 0, 1, REGB(0, 1));
    STAGE(A, m0, 1, 0, REGA(1, 0));
    STAGE(Bt, n0, 1, 0, REGB(1, 0));
    VMCNT4();
    ASM_BAR();

    for (int kt = 0; kt < NT; ++kt) {
      int d = kt & 1;
      int kc1 = (kt + 1 < NT) ? kt + 1 : NT - 1;
      int kc2 = (kt + 2 < NT) ? kt + 2 : NT - 1;
      char* A0 = REGA(d, 0); char* A1 = REGA(d, 1);
      char* B0 = REGB(d, 0); char* B1 = REGB(d, 1);
      char* An1 = REGA(d ^ 1, 1);
      char* Bn1 = REGB(d ^ 1, 1);

      short8 a[4], b[4];

      // ======== first half: kh0 (reads A0/B0; stages next-dbuf kh1) ========
#pragma unroll
      for (int ni = 0; ni < 4; ni++)
        b[ni] = *(const short8*)(B0 + (wave_n * 64 + ni * 16) * 64 + lane_off);
#pragma unroll
      for (int j = 0; j < 4; j++)
        a[j] = *(const short8*)(A0 + (wave_m * 128 + j * 16) * 64 + lane_off);
      STAGE(A, m0, kc1, 1, An1);
      __builtin_amdgcn_s_setprio(1);
#pragma unroll
      for (int j = 0; j < 4; j++)
#pragma unroll
        for (int ni = 0; ni < 4; ni++)
          acc[j][ni] = __builtin_amdgcn_mfma_f32_16x16x32_bf16(a[j], b[ni],
                                                               acc[j][ni], 0, 0, 0);
      __builtin_amdgcn_s_setprio(0);
#pragma unroll
      for (int j = 0; j < 4; j++)
        a[j] = *(const short8*)(A0 + (wave_m * 128 + (4 + j) * 16) * 64 + lane_off);
      STAGE(Bt, n0, kc1, 1, Bn1);
      __builtin_amdgcn_s_setprio(1);
#pragma unroll
      for (int j = 0; j < 4; j++)
#pragma unroll
        for (int ni = 0; ni < 4; ni++)
          acc[4 + j][ni] = __builtin_amdgcn_mfma_f32_16x16x32_bf16(
              a[j], b[ni], acc[4 + j][ni], 0, 0, 0);
      __builtin_amdgcn_s_setprio(0);
      ASM_BAR();  // bar_mid

      // ======== second half: kh1 (reads A1/B1; stages this-dbuf kh0) =======
#pragma unroll
      for (int ni = 0; ni < 4; ni++)
        b[ni] = *(const short8*)(B1 + (wave_n * 64 + ni * 16) * 64 + lane_off);
#pragma unroll
      for (int j = 0; j < 4; j++)
        a[j] = *(const short8*)(A1 + (wave_m * 128 + j * 16) * 64 + lane_off);
      STAGE(A, m0, kc2, 0, A0);
      __builtin_amdgcn_s_setprio(1);
#pragma unroll
      for (int j = 0; j < 4; j++)
#pragma unroll
        for (int ni = 0; ni < 4; ni++)
          acc[j][ni] = __builtin_amdgcn_mfma_f32_16x16x32_bf16(a[j], b[ni],
                                                               acc[j][ni], 0, 0, 0);
      __builtin_amdgcn_s_setprio(0);
#pragma unroll
      for (int j = 0; j < 4; j++)
        a[j] = *(const short8*)(A1 + (wave_m * 128 + (4 + j) * 16) * 64 + lane_off);
      STAGE(Bt, n0, kc2, 0, B0);
      __builtin_amdgcn_s_setprio(1);
#pragma unroll
      for (int j = 0; j < 4; j++)
#pragma unroll
        for (int ni = 0; ni < 4; ni++)
          acc[4 + j][ni] = __builtin_amdgcn_mfma_f32_16x16x32_bf16(
              a[j], b[ni], acc[4 + j][ni], 0, 0, 0);
      __builtin_amdgcn_s_setprio(0);
      VMCNT4();
      ASM_BAR();  // bar_end
    }
    VMCNT0();

    int r0 = g * 4;
#pragma unroll
    for (int mi = 0; mi < 8; mi++)
#pragma unroll
      for (int ni = 0; ni < 4; ni++) {
        int col = n0 + wave_n * 64 + ni * 16 + r15;
        float bv = bv4[ni];
#pragma unroll
        for (int r = 0; r < 4; r++) {
          int row = m0 + wave_m * 128 + mi * 16 + r0 + r;
          float v = acc[mi][ni][r] + bv;
          v = v / (1.0f + __expf(-v));  // silu
          out[(size_t)row * N + col] = __float2bfloat16(v);
        }
      }
  }
#undef STAGE
#undef REGA
#undef REGB
}

// ---------------------------------------------------------------------------
// GEMM2 wide: block = 128 rows x FULL N=256, 8 waves of 64x64 (2M x 4N),
// acc[4][4]=64 VGPR (R7's spill was acc[4][8]/4-wave — geometry here keeps
// the proven per-wave register footprint). A(h) staged exactly once; ~202
// active blocks = single round. Fused scatter epilogue to d_out.
// ---------------------------------------------------------------------------
__global__ __launch_bounds__(512, 2)
void gemm2_wide(const __hip_bfloat16* __restrict__ A,
                const __hip_bfloat16* __restrict__ Bt,
                const float* __restrict__ bias,
                const int* __restrict__ tpos,
                const float* __restrict__ pos_emb,
                float* __restrict__ out,
                const int* __restrict__ total_ptr) {
  constexpr int K = FOURH;  // 1024
  int m0 = blockIdx.x * 128;
  int total = total_ptr[0];
  int padded = (total + 127) & ~127;
  if (m0 >= padded) return;

  __shared__ __hip_bfloat16 As[128 * 64];  // 16KB
  __shared__ __hip_bfloat16 Bs[256 * 64];  // 32KB
  int tid = threadIdx.x;
  int lane = tid & 63, w = tid >> 6;
  int wave_m = w >> 2;  // 0..1
  int wave_n = w & 3;   // 0..3
  int wm = wave_m * 64, wn = wave_n * 64;

  int srow = lane >> 3;
  int scol = (lane & 7) * 8;
  int r15 = lane & 15, g = lane >> 4;

  f32x4 acc[4][4] = {};

  for (int k0 = 0; k0 < K; k0 += 64) {
    // A: 16 chunks of 1KB (8 rows each); wave w stages 2
#pragma unroll
    for (int i = 0; i < 2; i++) {
      int c = w * 2 + i;
      int row = c * 8 + srow;
      __builtin_amdgcn_global_load_lds(
          (gbl_void*)&A[(size_t)(m0 + row) * K + k0 + scol],
          (lds_void*)(As + c * 512), 16, 0, 0);
    }
    // B: 32 chunks; wave w stages 4
#pragma unroll
    for (int i = 0; i < 4; i++) {
      int c = w * 4 + i;
      int row = c * 8 + srow;
      __builtin_amdgcn_global_load_lds(
          (gbl_void*)&Bt[(size_t)row * K + k0 + scol],
          (lds_void*)(Bs + c * 512), 16, 0, 0);
    }
    __syncthreads();
#pragma unroll
    for (int kk = 0; kk < 64; kk += 32) {
      short8 a[4], bb[4];
#pragma unroll
      for (int m = 0; m < 4; m++)
        a[m] = *(const short8*)&As[(wm + m * 16 + r15) * 64 + kk + 8 * g];
#pragma unroll
      for (int n = 0; n < 4; n++)
        bb[n] = *(const short8*)&Bs[(wn + n * 16 + r15) * 64 + kk + 8 * g];
#pragma unroll
      for (int m = 0; m < 4; m++)
#pragma unroll
        for (int n = 0; n < 4; n++)
          acc[m][n] = __builtin_amdgcn_mfma_f32_16x16x32_bf16(a[m], bb[n],
                                                              acc[m][n], 0, 0, 0);
    }
    __syncthreads();
  }

  int r0 = g * 4;
#pragma unroll
  for (int m = 0; m < 4; m++) {
#pragma unroll
    for (int r = 0; r < 4; r++) {
      int row = m0 + wm + m * 16 + r0 + r;
      if (row >= total) continue;
      int pa = tpos[row];
      if (pa < 0) continue;
      int p = pa & (MAXT - 1);
#pragma unroll
      for (int n = 0; n < 4; n++) {
        int col = wn + n * 16 + r15;
        float v = acc[m][n][r] + bias[col] + pos_emb[p * H_ + col];
        out[(size_t)pa * H_ + col] = v;
      }
    }
  }
}

// ---------------------------------------------------------------------------
// merge2: sep rows (sep_token + pos_emb), zero-fill empty positions, mm.
// ---------------------------------------------------------------------------
__global__ void merge2_kernel(const int* __restrict__ gids,
                              const int* __restrict__ lengths,
                              const float* __restrict__ sep_token,
                              const float* __restrict__ pos_emb,
                              float* __restrict__ out) {
  int b = blockIdx.x, t = threadIdx.x;
  __shared__ signed char src[MAXT];
  __shared__ int g[L_];
  __shared__ int sh_total;
  int len = lengths[b];
  src[t] = 0;
  for (int l = t; l < len; l += 256) g[l] = gids[b * L_ + l];
  __syncthreads();
  if (t == 0) {
    int nsep = 0;
    for (int l = 0; l + 1 < len; l++)
      if (g[l] != g[l + 1]) nsep++;
    int total = len + nsep;
    sh_total = total;
    int off = MAXT - total;
    int sb = 0;
    for (int l = 0; l < len; l++) {
      int ti = off + l + sb;
      if (ti >= 0) src[ti] = 2;
      if (l + 1 < len && g[l] != g[l + 1]) {
        if (ti + 1 >= 0) src[ti + 1] = 1;
        sb++;
      }
    }
  }
  __syncthreads();
  int total = sh_total;
  int mlen = min(total, MAXT);

  int q = t >> 6, lane = t & 63, c4 = lane * 4;
  float4 sep4 = *(const float4*)&sep_token[c4];
  float* orow = out + (size_t)b * MAXT * H_;
  for (int p0 = 0; p0 < MAXT; p0 += 4) {
    int p = p0 + q;
    int s = src[p];
    if (s == 2) continue;
    float4 v;
    if (s == 1) {
      float4 pe = *(const float4*)&pos_emb[p * H_ + c4];
      v.x = sep4.x + pe.x; v.y = sep4.y + pe.y;
      v.z = sep4.z + pe.z; v.w = sep4.w + pe.w;
    } else {
      v.x = 0.f; v.y = 0.f; v.z = 0.f; v.w = 0.f;
    }
    *(float4*)&orow[(size_t)p * H_ + c4] = v;
  }
  float* mm = out + (size_t)B_ * MAXT * H_;
  mm[b * MAXT + t] = (t >= MAXT - mlen) ? 1.0f : 0.0f;
}

// ---------------------------------------------------------------------------
// launch
// ---------------------------------------------------------------------------
extern "C" void kernel_launch(void* const* d_in, const int* in_sizes, int n_in,
                              void* d_out, int out_size, void* d_ws,
                              size_t ws_size, hipStream_t stream) {
  const int* tok0 = (const int*)d_in[0];
  const int* tok1 = (const int*)d_in[1];
  const int* tok2 = (const int*)d_in[2];
  const int* tok3 = (const int*)d_in[3];
  const int* tgap = (const int*)d_in[4];
  const int* gid  = (const int*)d_in[5];
  const int* lengths = (const int*)d_in[6];
  const float* token_emb = (const float*)d_in[7];
  const float* gamma = (const float*)d_in[8];
  const float* beta  = (const float*)d_in[9];
  const float* w1 = (const float*)d_in[10];
  const float* b1 = (const float*)d_in[11];
  const float* w2 = (const float*)d_in[12];
  const float* b2 = (const float*)d_in[13];
  const float* tg_emb = (const float*)d_in[14];
  const float* g_emb  = (const float*)d_in[15];
  const float* pos_emb = (const float*)d_in[16];
  const float* sep_tok = (const float*)d_in[17];

  // workspace layout (bytes):
  //   x     bf16 [<=51200][1536] @ 0          (157,286,400)
  //   h     bf16 [<=51200][1024] @ 157286400  (104,857,600)
  //   w1t   bf16 [1024][1536]    @ 262144000  (  3,145,728)
  //   w2t   bf16 [256][1024]     @ 265289728  (    524,288)
  //   offsets int[257]           @ 265814016  (      1,028)
  //   tpos  int  [<=51200]       @ 265815044  (    204,800)  [own buffer now:
  //                                            written pre-gemm1 by fused_pre]
  const size_t NEEDED = 266019844;
  if (ws_size < NEEDED) return;  // R0 established ws >= ~318MB

  char* ws = (char*)d_ws;
  __hip_bfloat16* x = (__hip_bfloat16*)ws;
  __hip_bfloat16* h = (__hip_bfloat16*)(ws + 157286400);
  __hip_bfloat16* w1t = (__hip_bfloat16*)(ws + 262144000);
  __hip_bfloat16* w2t = (__hip_bfloat16*)(ws + 265289728);
  int* offsets = (int*)(ws + 265814016);
  int* tpos = (int*)(ws + 265815044);

  fused_pre<<<B_, 256, 0, stream>>>(lengths, gid, offsets, tpos, x);

  transpose_both<<<1792, 256, 0, stream>>>(w1, w1t, w2, w2t);

  embed_ln_kernel<<<dim3(L_, B_), 384, 0, stream>>>(
      tok0, tok1, tok2, tok3, tgap, gid, lengths, offsets, token_emb, tg_emb,
      g_emb, gamma, beta, x);

  hipFuncSetAttribute((const void*)gemm1_8ph,
                      hipFuncAttributeMaxDynamicSharedMemorySize, 131072);
  gemm1_8ph<<<256, 512, 131072, stream>>>(x, w1t, b1, h, offsets + B_);

  gemm2_wide<<<NPOS / 128, 512, 0, stream>>>(h, w2t, b2, tpos, pos_emb,
                                             (float*)d_out, offsets + B_);

  merge2_kernel<<<B_, 256, 0, stream>>>(gid, lengths, sep_tok, pos_emb,
                                        (float*)d_out);
}